// Round 4
// baseline (22.953 us; speedup 1.0000x reference)
//
#include <hip/hip_runtime.h>
#include <math.h>

#define HDIM 1024
#define BDIM 128
#define BM 64
#define BN 64
#define BK 32

// ws layout:
//   [0, 4KB)            : invS (1024 f32)
//   [4KB, 4KB+512KB)    : Pt[k][b] = exp(A[b][k])   (1024 x 128 f32, transposed)
//   [4KB+512KB, ...)    : partial[ksp][B][H] f32    (up to 4 MB)

__global__ __launch_bounds__(256) void k_prep(const float* __restrict__ A,
                                              const float* __restrict__ U,
                                              float* __restrict__ invS,
                                              float* __restrict__ Pt) {
    const int t = threadIdx.x;
    const int blk = blockIdx.x;
    if (blk < HDIM) {
        // S[blk] = sum_j exp(U[blk, j])
        float4 u = *reinterpret_cast<const float4*>(U + (size_t)blk * HDIM + t * 4);
        float s = __expf(u.x) + __expf(u.y) + __expf(u.z) + __expf(u.w);
        #pragma unroll
        for (int off = 32; off > 0; off >>= 1)
            s += __shfl_down(s, off, 64);
        __shared__ float red[4];
        if ((t & 63) == 0) red[t >> 6] = s;
        __syncthreads();
        if (t == 0) {
            float tot = red[0] + red[1] + red[2] + red[3];
            invS[blk] = 1.0f / tot;
        }
    } else {
        // Pt[k][b] = exp(A[b][k]), b = blk - HDIM
        const int b = blk - HDIM;
        float4 a = *reinterpret_cast<const float4*>(A + (size_t)b * HDIM + t * 4);
        const int k = t * 4;
        Pt[(size_t)(k + 0) * BDIM + b] = __expf(a.x);
        Pt[(size_t)(k + 1) * BDIM + b] = __expf(a.y);
        Pt[(size_t)(k + 2) * BDIM + b] = __expf(a.z);
        Pt[(size_t)(k + 3) * BDIM + b] = __expf(a.w);
    }
}

// out_partial[ks][b][j] = sum_{k in ks-chunk} Pt[k][b] * exp(U[k][j]) * invS[k]
__global__ __launch_bounds__(256) void k_mm(const float* __restrict__ U,
                                            const float* __restrict__ invS,
                                            const float* __restrict__ Pt,
                                            float* __restrict__ partial,
                                            int kchunk) {
    const int nt = blockIdx.x;   // j tile   (H/BN)
    const int mt = blockIdx.y;   // b tile   (B/BM)
    const int ks = blockIdx.z;   // k split
    const int t  = threadIdx.x;
    const int j0 = nt * BN;
    const int b0 = mt * BM;
    const int k0 = ks * kchunk;

    __shared__ float Pl[BK][BM];
    __shared__ float Ql[BK][BN];

    const int tj = t & 15;       // 0..15 -> 4 j's each
    const int tb = t >> 4;       // 0..15 -> 4 b's each
    const int srow  = t >> 4;    // staging: 16 rows/pass
    const int scol4 = (t & 15) * 4;

    float acc[4][4];
    #pragma unroll
    for (int i = 0; i < 4; ++i)
        #pragma unroll
        for (int j = 0; j < 4; ++j) acc[i][j] = 0.0f;

    for (int kt = 0; kt < kchunk; kt += BK) {
        const int kb = k0 + kt;
        #pragma unroll
        for (int pass = 0; pass < 2; ++pass) {
            const int k = pass * 16 + srow;
            float4 p = *reinterpret_cast<const float4*>(Pt + (size_t)(kb + k) * BDIM + b0 + scol4);
            *reinterpret_cast<float4*>(&Pl[k][scol4]) = p;
            float4 u = *reinterpret_cast<const float4*>(U + (size_t)(kb + k) * HDIM + j0 + scol4);
            const float is = invS[kb + k];
            float4 q;
            q.x = __expf(u.x) * is;
            q.y = __expf(u.y) * is;
            q.z = __expf(u.z) * is;
            q.w = __expf(u.w) * is;
            *reinterpret_cast<float4*>(&Ql[k][scol4]) = q;
        }
        __syncthreads();
        #pragma unroll
        for (int kk = 0; kk < BK; ++kk) {
            float4 p = *reinterpret_cast<const float4*>(&Pl[kk][tb * 4]);
            float4 q = *reinterpret_cast<const float4*>(&Ql[kk][tj * 4]);
            float pr[4] = {p.x, p.y, p.z, p.w};
            float qr[4] = {q.x, q.y, q.z, q.w};
            #pragma unroll
            for (int i = 0; i < 4; ++i)
                #pragma unroll
                for (int j = 0; j < 4; ++j)
                    acc[i][j] = fmaf(pr[i], qr[j], acc[i][j]);
        }
        __syncthreads();
    }

    float* pbase = partial + (size_t)ks * BDIM * HDIM;
    #pragma unroll
    for (int i = 0; i < 4; ++i) {
        const int b = b0 + tb * 4 + i;
        float4 v = make_float4(acc[i][0], acc[i][1], acc[i][2], acc[i][3]);
        *reinterpret_cast<float4*>(pbase + (size_t)b * HDIM + j0 + tj * 4) = v;
    }
}

__global__ __launch_bounds__(256) void k_comb(const float* __restrict__ partial,
                                              float* __restrict__ out,
                                              int ksp) {
    const int idx = blockIdx.x * 256 + threadIdx.x;  // 0 .. B*H-1
    float s = 0.0f;
    for (int ks = 0; ks < ksp; ++ks)
        s += partial[(size_t)ks * BDIM * HDIM + idx];
    out[idx] = logf(s);
}

extern "C" void kernel_launch(void* const* d_in, const int* in_sizes, int n_in,
                              void* d_out, int out_size, void* d_ws, size_t ws_size,
                              hipStream_t stream) {
    const float* A = (const float*)d_in[0];   // log_alpha  (128 x 1024)
    const float* U = (const float*)d_in[1];   // unnormalized_tran (1024 x 1024)
    float* out = (float*)d_out;               // (128 x 1024) f32

    char* ws = (char*)d_ws;
    float* invS = (float*)ws;                                     // 4 KB
    float* Pt   = (float*)(ws + 4096);                            // 512 KB
    float* partial = (float*)(ws + 4096 + (size_t)HDIM * BDIM * 4);

    // pick K-split count that fits in ws
    const size_t base_need = 4096 + (size_t)HDIM * BDIM * 4;
    int ksp = 8;
    while (ksp > 1 && base_need + (size_t)ksp * BDIM * HDIM * 4 > ws_size) ksp >>= 1;
    const int kchunk = HDIM / ksp;

    k_prep<<<HDIM + BDIM, 256, 0, stream>>>(A, U, invS, Pt);
    dim3 g(HDIM / BN, BDIM / BM, ksp);
    k_mm<<<g, 256, 0, stream>>>(U, invS, Pt, partial, kchunk);
    k_comb<<<(BDIM * HDIM) / 256, 256, 0, stream>>>(partial, out, ksp);
}

// Round 5
// 22.486 us; speedup vs baseline: 1.0207x; 1.0207x over previous
//
#include <hip/hip_runtime.h>
#include <math.h>

#define H 1024
#define B 128
#define KSP 32           // K-split count; BK = H/KSP
#define BK 32
#define BN 128           // N-tile; grid.x = H/BN = 8
#define LP 132           // padded LDS row (f32), mult-4 for b128 alignment

typedef unsigned short u16;
typedef unsigned int u32;

static __device__ inline u16 f2bf(float x) {
    u32 u = __builtin_bit_cast(u32, x);
    u32 r = (u + 0x7FFFu + ((u >> 16) & 1u)) >> 16;   // RTNE
    return (u16)r;
}

// ---- kA: invS[i] = 1 / sum_j exp(U[i][j]) ---------------------------------
__global__ __launch_bounds__(256) void kA(const float* __restrict__ U,
                                          float* __restrict__ invS) {
    const int t = threadIdx.x;
    const int r = blockIdx.x;
    float4 u = *reinterpret_cast<const float4*>(U + (size_t)r * H + t * 4);
    float s = __expf(u.x) + __expf(u.y) + __expf(u.z) + __expf(u.w);
    #pragma unroll
    for (int off = 32; off > 0; off >>= 1)
        s += __shfl_down(s, off, 64);
    __shared__ float red[4];
    if ((t & 63) == 0) red[t >> 6] = s;
    __syncthreads();
    if (t == 0) invS[r] = 1.0f / (red[0] + red[1] + red[2] + red[3]);
}

// ---- kC: partial[ks][b][j] = sum_{k in BK slice} exp(A[b][k]) * exp(U[k][j]) * invS[k]
// one block: full M (128) x BN (128), single BK=32 staging phase, 8x8/thread
__global__ __launch_bounds__(256) void kC(const float* __restrict__ A,
                                          const float* __restrict__ U,
                                          const float* __restrict__ invS,
                                          u16* __restrict__ partial) {
    const int t  = threadIdx.x;
    const int j0 = blockIdx.x * BN;      // 0..7
    const int ks = blockIdx.y;           // 0..31
    const int k0 = ks * BK;

    __shared__ float Pl[BK][LP];   // Pl[k][b] = exp(A[b][k0+k])
    __shared__ float Ql[BK][LP];   // Ql[k][j] = exp(U[k0+k][j0+j]) * invS[k0+k]

    // stage P (transposed scatter) : A rows all 128, cols k0..k0+31
    {
        const int c = (t & 7) * 4;          // k within tile
        #pragma unroll
        for (int p = 0; p < 4; ++p) {
            const int b = (t >> 3) + 32 * p;
            float4 a = *reinterpret_cast<const float4*>(A + (size_t)b * H + k0 + c);
            Pl[c + 0][b] = __expf(a.x);
            Pl[c + 1][b] = __expf(a.y);
            Pl[c + 2][b] = __expf(a.z);
            Pl[c + 3][b] = __expf(a.w);
        }
    }
    // stage Q (natural layout)
    {
        const int k = t >> 3;
        const float is = invS[k0 + k];
        const float* Urow = U + (size_t)(k0 + k) * H + j0;
        #pragma unroll
        for (int p = 0; p < 4; ++p) {
            const int j = (t & 7) * 4 + 32 * p;
            float4 u = *reinterpret_cast<const float4*>(Urow + j);
            float4 q;
            q.x = __expf(u.x) * is;
            q.y = __expf(u.y) * is;
            q.z = __expf(u.z) * is;
            q.w = __expf(u.w) * is;
            *reinterpret_cast<float4*>(&Ql[k][j]) = q;
        }
    }
    __syncthreads();

    const int tb = t >> 4;   // 0..15 -> 8 b-rows each
    const int tj = t & 15;   // 0..15 -> 8 j-cols each

    float acc[8][8];
    #pragma unroll
    for (int i = 0; i < 8; ++i)
        #pragma unroll
        for (int j = 0; j < 8; ++j) acc[i][j] = 0.0f;

    #pragma unroll 4
    for (int kk = 0; kk < BK; ++kk) {
        float4 p0 = *reinterpret_cast<const float4*>(&Pl[kk][tb * 8]);
        float4 p1 = *reinterpret_cast<const float4*>(&Pl[kk][tb * 8 + 4]);
        float4 q0 = *reinterpret_cast<const float4*>(&Ql[kk][tj * 8]);
        float4 q1 = *reinterpret_cast<const float4*>(&Ql[kk][tj * 8 + 4]);
        float pr[8] = {p0.x, p0.y, p0.z, p0.w, p1.x, p1.y, p1.z, p1.w};
        float qr[8] = {q0.x, q0.y, q0.z, q0.w, q1.x, q1.y, q1.z, q1.w};
        #pragma unroll
        for (int i = 0; i < 8; ++i)
            #pragma unroll
            for (int j = 0; j < 8; ++j)
                acc[i][j] = fmaf(pr[i], qr[j], acc[i][j]);
    }

    // epilogue: pack 8 bf16 per row -> one 16B store
    u16* pbase = partial + (size_t)ks * (B * H) + j0 + tj * 8;
    #pragma unroll
    for (int i = 0; i < 8; ++i) {
        const int b = tb * 8 + i;
        uint4 v;
        v.x = (u32)f2bf(acc[i][0]) | ((u32)f2bf(acc[i][1]) << 16);
        v.y = (u32)f2bf(acc[i][2]) | ((u32)f2bf(acc[i][3]) << 16);
        v.z = (u32)f2bf(acc[i][4]) | ((u32)f2bf(acc[i][5]) << 16);
        v.w = (u32)f2bf(acc[i][6]) | ((u32)f2bf(acc[i][7]) << 16);
        *reinterpret_cast<uint4*>(pbase + (size_t)b * H) = v;
    }
}

// ---- kD: out = log(sum_ks partial) ----------------------------------------
__global__ __launch_bounds__(256) void kD(const u16* __restrict__ partial,
                                          float* __restrict__ out) {
    const int idx4 = (blockIdx.x * 256 + threadIdx.x) * 4;   // 4 outputs/thread
    float s0 = 0.f, s1 = 0.f, s2 = 0.f, s3 = 0.f;
    #pragma unroll 8
    for (int ks = 0; ks < KSP; ++ks) {
        ushort4 q = *reinterpret_cast<const ushort4*>(partial + ((size_t)ks << 17) + idx4);
        s0 += __builtin_bit_cast(float, (u32)q.x << 16);
        s1 += __builtin_bit_cast(float, (u32)q.y << 16);
        s2 += __builtin_bit_cast(float, (u32)q.z << 16);
        s3 += __builtin_bit_cast(float, (u32)q.w << 16);
    }
    float4 o;
    o.x = __logf(s0); o.y = __logf(s1); o.z = __logf(s2); o.w = __logf(s3);
    *reinterpret_cast<float4*>(out + idx4) = o;
}

extern "C" void kernel_launch(void* const* d_in, const int* in_sizes, int n_in,
                              void* d_out, int out_size, void* d_ws, size_t ws_size,
                              hipStream_t stream) {
    const float* A = (const float*)d_in[0];   // log_alpha (128 x 1024)
    const float* U = (const float*)d_in[1];   // unnormalized_tran (1024 x 1024)
    float* out = (float*)d_out;               // (128 x 1024) f32

    char* ws = (char*)d_ws;
    float* invS  = (float*)ws;                 // 4 KB
    u16* partial = (u16*)(ws + 4096);          // KSP * 128 * 1024 * 2 B = 8 MB

    kA<<<H, 256, 0, stream>>>(U, invS);
    dim3 gC(H / BN, KSP);
    kC<<<gC, 256, 0, stream>>>(A, U, invS, partial);
    kD<<<(B * H) / (256 * 4), 256, 0, stream>>>(partial, out);
}